// Round 1
// baseline (484.593 us; speedup 1.0000x reference)
//
#include <hip/hip_runtime.h>

#define BT 128
#define D  256
#define H  512

// Output element offsets (flat fp32, reference return order)
#define OFF_HT  0          // (BT, 2H)  = 131072
#define OFF_C1  131072     // (BT, H)   = 65536
#define OFF_C2  196608
#define OFF_N1  262144
#define OFF_N2  327680
#define OFF_T1  393216
#define OFF_T2  458752
#define OFF_W11 524288     // (BT, D, H) = 16777216
#define OFF_W12 17301504
#define OFF_W21 34078720
#define OFF_W22 50855936

// Kernel 1: per-(b,h) work — xw dot products, c/n/t traces, h_t, and
// coefficient stash (A,B,g) into ws for the big kernel.
__global__ __launch_bounds__(256) void rtu_small(
    const float* __restrict__ x_t,
    const float* __restrict__ h1,  const float* __restrict__ h2,
    const float* __restrict__ mnu1, const float* __restrict__ mnu2,
    const float* __restrict__ mth1, const float* __restrict__ mth2,
    const float* __restrict__ w1,  const float* __restrict__ w2,
    const float* __restrict__ nu_log, const float* __restrict__ theta_log,
    float* __restrict__ out, float* __restrict__ ws)
{
    __shared__ float xs[D];
    const int tid = threadIdx.x;
    const int idx = blockIdx.x * 256 + tid;     // idx == b*H + h
    const int b   = idx >> 9;                   // uniform per block (2 blocks per b)
    const int h   = idx & (H - 1);

    // stage x_t row for this b (D == blockDim.x == 256)
    xs[tid] = x_t[b * D + tid];
    __syncthreads();

    // per-h coefficients
    const float nl = nu_log[h];
    const float tl = theta_log[h];
    const float exp_nu = expf(nl);
    const float r      = expf(-exp_nu);
    const float theta  = expf(tl);
    const float g      = sqrtf(fmaxf(1.0f - r * r, 0.0f));
    float s, c;
    sincosf(theta, &s, &c);
    const float A = r * c;
    const float B = r * s;
    const float dA_dnu = -A * exp_nu;
    const float dB_dnu = -B * exp_nu;
    const float dg_dnu = (r * r) * exp_nu / g;
    const float dA_dth = -B * theta;
    const float dB_dth =  A * theta;

    // stash A,B,g for the big kernel (only once)
    if (b == 0) {
        ws[h]            = A;
        ws[H + h]        = B;
        ws[2 * H + h]    = g;
    }

    // xw1/xw2: dot over D with coalesced w reads (lanes read contiguous h)
    float xw1 = 0.0f, xw2 = 0.0f;
    #pragma unroll 8
    for (int d = 0; d < D; ++d) {
        const float xv = xs[d];
        xw1 = fmaf(xv, w1[d * H + h], xw1);
        xw2 = fmaf(xv, w2[d * H + h], xw2);
    }

    const float h1v = h1[idx],  h2v = h2[idx];
    const float mn1 = mnu1[idx], mn2 = mnu2[idx];
    const float mt1 = mth1[idx], mt2 = mth2[idx];

    const float c1v = A * h1v - B * h2v + g * xw1;
    const float c2v = B * h1v + A * h2v + g * xw2;

    const float n1v = A * mn1 - B * mn2 + dA_dnu * h1v - dB_dnu * h2v + dg_dnu * xw1;
    const float n2v = B * mn1 + A * mn2 + dB_dnu * h1v + dA_dnu * h2v + dg_dnu * xw2;

    const float t1v = A * mt1 - B * mt2 + dA_dth * h1v - dB_dth * h2v;
    const float t2v = B * mt1 + A * mt2 + dB_dth * h1v + dA_dth * h2v;

    out[OFF_HT + b * (2 * H) + h]     = fmaxf(c1v, 0.0f);
    out[OFF_HT + b * (2 * H) + H + h] = fmaxf(c2v, 0.0f);
    out[OFF_C1 + idx] = c1v;
    out[OFF_C2 + idx] = c2v;
    out[OFF_N1 + idx] = n1v;
    out[OFF_N2 + idx] = n2v;
    out[OFF_T1 + idx] = t1v;
    out[OFF_T2 + idx] = t2v;
}

// Kernel 2: the bandwidth kernel — 4 float4 reads, 4 float4 writes per thread.
__global__ __launch_bounds__(256) void rtu_big(
    const float4* __restrict__ mw11, const float4* __restrict__ mw12,
    const float4* __restrict__ mw21, const float4* __restrict__ mw22,
    const float* __restrict__ x_t,
    const float* __restrict__ ws,
    float* __restrict__ out)
{
    const int e  = blockIdx.x * 256 + threadIdx.x;   // float4 index, 0..4194303
    const int hq = e & 127;                           // h/4
    const int bd = e >> 7;                            // b*D + d (x_t is (BT,D) flat)

    const float x = x_t[bd];

    const float4 A4 = ((const float4*)(ws))[hq];
    const float4 B4 = ((const float4*)(ws + H))[hq];
    const float4 g4 = ((const float4*)(ws + 2 * H))[hq];

    const float4 m11 = mw11[e];
    const float4 m12 = mw12[e];
    const float4 m21 = mw21[e];
    const float4 m22 = mw22[e];

    float4 o11, o12, o21, o22;

    const float gx_x = g4.x * x, gx_y = g4.y * x, gx_z = g4.z * x, gx_w = g4.w * x;

    o11.x = fmaf(A4.x, m11.x, fmaf(-B4.x, m12.x, gx_x));
    o11.y = fmaf(A4.y, m11.y, fmaf(-B4.y, m12.y, gx_y));
    o11.z = fmaf(A4.z, m11.z, fmaf(-B4.z, m12.z, gx_z));
    o11.w = fmaf(A4.w, m11.w, fmaf(-B4.w, m12.w, gx_w));

    o12.x = fmaf(B4.x, m11.x, A4.x * m12.x);
    o12.y = fmaf(B4.y, m11.y, A4.y * m12.y);
    o12.z = fmaf(B4.z, m11.z, A4.z * m12.z);
    o12.w = fmaf(B4.w, m11.w, A4.w * m12.w);

    o21.x = fmaf(A4.x, m21.x, -B4.x * m22.x);
    o21.y = fmaf(A4.y, m21.y, -B4.y * m22.y);
    o21.z = fmaf(A4.z, m21.z, -B4.z * m22.z);
    o21.w = fmaf(A4.w, m21.w, -B4.w * m22.w);

    o22.x = fmaf(B4.x, m21.x, fmaf(A4.x, m22.x, gx_x));
    o22.y = fmaf(B4.y, m21.y, fmaf(A4.y, m22.y, gx_y));
    o22.z = fmaf(B4.z, m21.z, fmaf(A4.z, m22.z, gx_z));
    o22.w = fmaf(B4.w, m21.w, fmaf(A4.w, m22.w, gx_w));

    ((float4*)(out + OFF_W11))[e] = o11;
    ((float4*)(out + OFF_W12))[e] = o12;
    ((float4*)(out + OFF_W21))[e] = o21;
    ((float4*)(out + OFF_W22))[e] = o22;
}

extern "C" void kernel_launch(void* const* d_in, const int* in_sizes, int n_in,
                              void* d_out, int out_size, void* d_ws, size_t ws_size,
                              hipStream_t stream) {
    const float* x_t   = (const float*)d_in[0];
    const float* h1    = (const float*)d_in[1];
    const float* h2    = (const float*)d_in[2];
    const float* mnu1  = (const float*)d_in[3];
    const float* mnu2  = (const float*)d_in[4];
    const float* mth1  = (const float*)d_in[5];
    const float* mth2  = (const float*)d_in[6];
    const float* mw11  = (const float*)d_in[7];
    const float* mw12  = (const float*)d_in[8];
    const float* mw21  = (const float*)d_in[9];
    const float* mw22  = (const float*)d_in[10];
    const float* w1    = (const float*)d_in[11];
    const float* w2    = (const float*)d_in[12];
    const float* nu_log    = (const float*)d_in[13];
    const float* theta_log = (const float*)d_in[14];

    float* out = (float*)d_out;
    float* ws  = (float*)d_ws;

    // Kernel 1: (BT*H)/256 = 256 blocks. Also writes A/B/g coefs into ws.
    rtu_small<<<(BT * H) / 256, 256, 0, stream>>>(
        x_t, h1, h2, mnu1, mnu2, mth1, mth2, w1, w2, nu_log, theta_log, out, ws);

    // Kernel 2: (BT*D*H/4)/256 = 16384 blocks.
    rtu_big<<<(BT * D * H / 4) / 256, 256, 0, stream>>>(
        (const float4*)mw11, (const float4*)mw12, (const float4*)mw21,
        (const float4*)mw22, x_t, ws, out);
}

// Round 2
// 464.265 us; speedup vs baseline: 1.0438x; 1.0438x over previous
//
#include <hip/hip_runtime.h>

#define BT 128
#define D  256
#define H  512

// Output element offsets (flat fp32, reference return order)
#define OFF_HT  0          // (BT, 2H)  = 131072
#define OFF_C1  131072     // (BT, H)   = 65536
#define OFF_C2  196608
#define OFF_N1  262144
#define OFF_N2  327680
#define OFF_T1  393216
#define OFF_T2  458752
#define OFF_W11 524288     // (BT, D, H) = 16777216
#define OFF_W12 17301504
#define OFF_W21 34078720
#define OFF_W22 50855936

#define SMALL_BLOCKS 256          // (BT*H)/256
#define BIG_BLOCKS   16384        // (BT*D*H/4)/256

// Fused kernel.
//  blocks [0, 256):        per-(b,h) work — xw dot products, c/n/t traces, h_t
//  blocks [256, 16640):    W-trace bandwidth work; A/B/g recomputed per block
//                          into LDS (VALU is idle in this memory-bound phase)
__global__ __launch_bounds__(256) void rtu_fused(
    const float*  __restrict__ x_t,
    const float*  __restrict__ h1,   const float* __restrict__ h2,
    const float*  __restrict__ mnu1, const float* __restrict__ mnu2,
    const float*  __restrict__ mth1, const float* __restrict__ mth2,
    const float4* __restrict__ mw11, const float4* __restrict__ mw12,
    const float4* __restrict__ mw21, const float4* __restrict__ mw22,
    const float*  __restrict__ w1,   const float* __restrict__ w2,
    const float*  __restrict__ nu_log, const float* __restrict__ theta_log,
    float* __restrict__ out)
{
    __shared__ float sA[H];
    __shared__ float sB[H];
    __shared__ float sG[H];
    __shared__ float xs[D];

    const int tid = threadIdx.x;

    if (blockIdx.x < SMALL_BLOCKS) {
        // ---------------- small path: one thread per (b,h) ----------------
        const int idx = blockIdx.x * 256 + tid;     // idx == b*H + h
        const int b   = idx >> 9;                   // uniform per block
        const int h   = idx & (H - 1);

        xs[tid] = x_t[b * D + tid];
        __syncthreads();

        const float exp_nu = expf(nu_log[h]);
        const float r      = expf(-exp_nu);
        const float theta  = expf(theta_log[h]);
        const float g      = sqrtf(fmaxf(1.0f - r * r, 0.0f));
        float s, c;
        sincosf(theta, &s, &c);
        const float A = r * c;
        const float B = r * s;
        const float dA_dnu = -A * exp_nu;
        const float dB_dnu = -B * exp_nu;
        const float dg_dnu = (r * r) * exp_nu / g;
        const float dA_dth = -B * theta;
        const float dB_dth =  A * theta;

        float xw1 = 0.0f, xw2 = 0.0f;
        #pragma unroll 8
        for (int d = 0; d < D; ++d) {
            const float xv = xs[d];
            xw1 = fmaf(xv, w1[d * H + h], xw1);
            xw2 = fmaf(xv, w2[d * H + h], xw2);
        }

        const float h1v = h1[idx],  h2v = h2[idx];
        const float mn1 = mnu1[idx], mn2 = mnu2[idx];
        const float mt1 = mth1[idx], mt2 = mth2[idx];

        const float c1v = A * h1v - B * h2v + g * xw1;
        const float c2v = B * h1v + A * h2v + g * xw2;

        const float n1v = A * mn1 - B * mn2 + dA_dnu * h1v - dB_dnu * h2v + dg_dnu * xw1;
        const float n2v = B * mn1 + A * mn2 + dB_dnu * h1v + dA_dnu * h2v + dg_dnu * xw2;

        const float t1v = A * mt1 - B * mt2 + dA_dth * h1v - dB_dth * h2v;
        const float t2v = B * mt1 + A * mt2 + dB_dth * h1v + dA_dth * h2v;

        out[OFF_HT + b * (2 * H) + h]     = fmaxf(c1v, 0.0f);
        out[OFF_HT + b * (2 * H) + H + h] = fmaxf(c2v, 0.0f);
        out[OFF_C1 + idx] = c1v;
        out[OFF_C2 + idx] = c2v;
        out[OFF_N1 + idx] = n1v;
        out[OFF_N2 + idx] = n2v;
        out[OFF_T1 + idx] = t1v;
        out[OFF_T2 + idx] = t2v;
        return;
    }

    // ---------------- big path: W-trace bandwidth work ----------------
    // Recompute A/B/g for all 512 h into LDS (2 per thread).
    #pragma unroll
    for (int i = 0; i < 2; ++i) {
        const int h = tid + i * 256;
        const float exp_nu = expf(nu_log[h]);
        const float r      = expf(-exp_nu);
        const float theta  = expf(theta_log[h]);
        float s, c;
        sincosf(theta, &s, &c);
        sA[h] = r * c;
        sB[h] = r * s;
        sG[h] = sqrtf(fmaxf(1.0f - r * r, 0.0f));
    }
    __syncthreads();

    const int e  = (blockIdx.x - SMALL_BLOCKS) * 256 + tid;  // float4 index
    const int hq = e & 127;                                  // h/4
    const int bd = e >> 7;                                   // b*D + d

    const float x = x_t[bd];

    const float4 A4 = ((const float4*)sA)[hq];
    const float4 B4 = ((const float4*)sB)[hq];
    const float4 g4 = ((const float4*)sG)[hq];

    const float4 m11 = mw11[e];
    const float4 m12 = mw12[e];
    const float4 m21 = mw21[e];
    const float4 m22 = mw22[e];

    const float gx_x = g4.x * x, gx_y = g4.y * x, gx_z = g4.z * x, gx_w = g4.w * x;

    float4 o11, o12, o21, o22;

    o11.x = fmaf(A4.x, m11.x, fmaf(-B4.x, m12.x, gx_x));
    o11.y = fmaf(A4.y, m11.y, fmaf(-B4.y, m12.y, gx_y));
    o11.z = fmaf(A4.z, m11.z, fmaf(-B4.z, m12.z, gx_z));
    o11.w = fmaf(A4.w, m11.w, fmaf(-B4.w, m12.w, gx_w));

    o12.x = fmaf(B4.x, m11.x, A4.x * m12.x);
    o12.y = fmaf(B4.y, m11.y, A4.y * m12.y);
    o12.z = fmaf(B4.z, m11.z, A4.z * m12.z);
    o12.w = fmaf(B4.w, m11.w, A4.w * m12.w);

    o21.x = fmaf(A4.x, m21.x, -B4.x * m22.x);
    o21.y = fmaf(A4.y, m21.y, -B4.y * m22.y);
    o21.z = fmaf(A4.z, m21.z, -B4.z * m22.z);
    o21.w = fmaf(A4.w, m21.w, -B4.w * m22.w);

    o22.x = fmaf(B4.x, m21.x, fmaf(A4.x, m22.x, gx_x));
    o22.y = fmaf(B4.y, m21.y, fmaf(A4.y, m22.y, gx_y));
    o22.z = fmaf(B4.z, m21.z, fmaf(A4.z, m22.z, gx_z));
    o22.w = fmaf(B4.w, m21.w, fmaf(A4.w, m22.w, gx_w));

    ((float4*)(out + OFF_W11))[e] = o11;
    ((float4*)(out + OFF_W12))[e] = o12;
    ((float4*)(out + OFF_W21))[e] = o21;
    ((float4*)(out + OFF_W22))[e] = o22;
}

extern "C" void kernel_launch(void* const* d_in, const int* in_sizes, int n_in,
                              void* d_out, int out_size, void* d_ws, size_t ws_size,
                              hipStream_t stream) {
    const float* x_t   = (const float*)d_in[0];
    const float* h1    = (const float*)d_in[1];
    const float* h2    = (const float*)d_in[2];
    const float* mnu1  = (const float*)d_in[3];
    const float* mnu2  = (const float*)d_in[4];
    const float* mth1  = (const float*)d_in[5];
    const float* mth2  = (const float*)d_in[6];
    const float* mw11  = (const float*)d_in[7];
    const float* mw12  = (const float*)d_in[8];
    const float* mw21  = (const float*)d_in[9];
    const float* mw22  = (const float*)d_in[10];
    const float* w1    = (const float*)d_in[11];
    const float* w2    = (const float*)d_in[12];
    const float* nu_log    = (const float*)d_in[13];
    const float* theta_log = (const float*)d_in[14];

    float* out = (float*)d_out;

    rtu_fused<<<SMALL_BLOCKS + BIG_BLOCKS, 256, 0, stream>>>(
        x_t, h1, h2, mnu1, mnu2, mth1, mth2,
        (const float4*)mw11, (const float4*)mw12,
        (const float4*)mw21, (const float4*)mw22,
        w1, w2, nu_log, theta_log, out);
}